// Round 13
// baseline (3648.813 us; speedup 1.0000x reference)
//
#include <hip/hip_runtime.h>
#include <stdint.h>

#define B_SZ   256
#define T_SZ   1000
#define N_IN   128
#define UNITS  512
#define NT     192                // tail rows held in registers (320..511)
#define TST    (UNITS - NT)       // 320 = start of wave 5: tail = waves 5..7

// ---------------------------------------------------------------------------
// Phase 0: Wz[513][512]: W_rec with diag zeroed + all-zero row 512. Pad-slot
// (idx 512) and diagonal reads give exact +0.0f (proven r5..r11, absmax 0.0).
// ---------------------------------------------------------------------------
__global__ __launch_bounds__(512) void wz_prep(const float* __restrict__ Wr,
                                               float* __restrict__ Wz) {
    const int c = threadIdx.x, r = blockIdx.x;
    Wz[(size_t)r * UNITS + c] =
        (r >= UNITS || r == c) ? 0.0f : Wr[(size_t)r * UNITS + c];
}

// ---------------------------------------------------------------------------
// Phase 1: C[M,512] = X[M,128] @ W[128,512]  (unchanged, ~fp32 roofline)
// ---------------------------------------------------------------------------
__global__ __launch_bounds__(256) void gemm_in(const float* __restrict__ X,
                                               const float* __restrict__ W,
                                               float* __restrict__ C) {
    __shared__ __align__(16) float As[32][128];
    __shared__ __align__(16) float Bs[32][128];

    const int tid = threadIdx.x;
    const int ntile = blockIdx.x & 3;
    const int mtile = blockIdx.x >> 2;
    const int m0 = mtile * 128, n0 = ntile * 128;
    const int tm  = (tid >> 4) * 8;
    const int tn4 = (tid & 15) * 4;

    float acc[8][8];
#pragma unroll
    for (int i = 0; i < 8; ++i)
#pragma unroll
        for (int j = 0; j < 8; ++j) acc[i][j] = 0.0f;

    for (int k0 = 0; k0 < 128; k0 += 32) {
        __syncthreads();
#pragma unroll
        for (int r = 0; r < 4; ++r) {
            int li  = r * 256 + tid;
            int row = li >> 3;
            int ch  = li & 7;
            float4 a = *(const float4*)&X[(size_t)(m0 + row) * 128 + k0 + ch * 4];
            As[ch * 4 + 0][row] = a.x;
            As[ch * 4 + 1][row] = a.y;
            As[ch * 4 + 2][row] = a.z;
            As[ch * 4 + 3][row] = a.w;
        }
#pragma unroll
        for (int r = 0; r < 4; ++r) {
            int li = r * 256 + tid;
            int kk = li >> 5;
            int n4 = li & 31;
            *(float4*)&Bs[kk][n4 * 4] =
                *(const float4*)&W[(size_t)(k0 + kk) * 512 + n0 + n4 * 4];
        }
        __syncthreads();

#pragma unroll 8
        for (int k = 0; k < 32; ++k) {
            float4 a0 = *(const float4*)&As[k][tm];
            float4 a1 = *(const float4*)&As[k][tm + 4];
            float4 b0 = *(const float4*)&Bs[k][tn4];
            float4 b1 = *(const float4*)&Bs[k][tn4 + 64];
            const float av[8] = {a0.x, a0.y, a0.z, a0.w, a1.x, a1.y, a1.z, a1.w};
            const float bv[8] = {b0.x, b0.y, b0.z, b0.w, b1.x, b1.y, b1.z, b1.w};
#pragma unroll
            for (int i = 0; i < 8; ++i)
#pragma unroll
                for (int j = 0; j < 8; ++j)
                    acc[i][j] = fmaf(av[i], bv[j], acc[i][j]);
        }
    }

#pragma unroll
    for (int i = 0; i < 8; ++i) {
        size_t row = (size_t)(m0 + tm + i) * 512;
        float4 c0 = make_float4(acc[i][0], acc[i][1], acc[i][2], acc[i][3]);
        float4 c1 = make_float4(acc[i][4], acc[i][5], acc[i][6], acc[i][7]);
        *(float4*)&C[row + n0 + tn4]      = c0;
        *(float4*)&C[row + n0 + 64 + tn4] = c1;
    }
}

// ---------------------------------------------------------------------------
// Phase 2: ALIF scan. One WG per batch (grid 256, 512 thr), thread u owns
// unit u. The scan is pinned at the per-XCD L2-BW wall (~98% of 4.3 TB/s),
// so this round removes 37.5% of the L2 traffic at ZERO recurring cost:
// rows 320..511 of Wz live in per-thread REGISTERS (tw[192], preloaded once
// before the t-loop — W is constant across steps; occupancy is block-limited
// so ~224 VGPRs are free). The active-list prefix (j<320 = waves 0..4) keeps
// r1's proven 8-in-flight L2 loop untouched; the tail (waves 5..7) is 192
// wave-uniform scalar-branch adds from ballot masks (readfirstlane -> SGPR
// -> s_bitcmp/s_cbranch; only active rows execute a VALU add).
// Numerics: adds are exactly the nonzero terms in globally ascending j
// (prefix list ascending, then rows 320..511 ascending) — bit-identical to
// all passing rounds (absmax 0.0). Pads (idx 512) read the Wz zero row.
// ---------------------------------------------------------------------------
__global__ __launch_bounds__(512, 2) void alif_scan(const float* __restrict__ Wz,
                                                    float* __restrict__ IO) {
    __shared__ __align__(16) int s_list[TST + 16];   // ≤320 actives + 16 pad
    __shared__ int s_cnt[5];
    __shared__ int s_total;
    __shared__ unsigned long long s_tm[3];           // ballot masks, waves 5..7

    const int b = blockIdx.x;
    const int u = threadIdx.x;
    const int w = u >> 6;
    const int lane = u & 63;

    const float DECAY   = 0.95122942450071400910f;   // exp(-1/20)
    const float OMD     = 1.0f - DECAY;
    const float DECAY_B = 0.99501247919268232342f;   // exp(-1/200)
    const float OMDB    = 1.0f - DECAY_B;

    float v = 0.0f, ad = 0.0f, z = 0.0f;

    const float* wz = Wz + u;                         // column u of Wz
    float* io = IO + (size_t)b * (T_SZ * UNITS) + u;

    // ---- one-time: preload tail rows 320..511 of column u into registers --
    float tw[NT];
#pragma unroll
    for (int k = 0; k < NT; ++k)
        tw[k] = Wz[(size_t)(TST + k) * UNITS + u];    // diag already zeroed

    // ---- init shared state ----
    if (u < TST + 16) s_list[u] = UNITS;
    if (u < 5) s_cnt[u] = 0;
    if (u < 3) s_tm[u] = 0ull;
    if (u == 0) s_total = 0;
    __syncthreads();

    float i_cur = io[0];

#define RFL(x) ((unsigned)__builtin_amdgcn_readfirstlane((int)(x)))

    for (int t = 0; t < T_SZ; ++t) {
        // prefetch next step's input current
        float i_next = io[(t + 1 < T_SZ ? t + 1 : t) * UNITS];

        const int cnt = s_total;          // prefix actives (j < 320)

        // scalarize tail masks (block-uniform -> SGPR, uniform branches)
        unsigned long long v5 = s_tm[0], v6 = s_tm[1], v7 = s_tm[2];
        const unsigned long long M5 =
            RFL((unsigned)v5) | ((unsigned long long)RFL((unsigned)(v5 >> 32)) << 32);
        const unsigned long long M6 =
            RFL((unsigned)v6) | ((unsigned long long)RFL((unsigned)(v6 >> 32)) << 32);
        const unsigned long long M7 =
            RFL((unsigned)v7) | ((unsigned long long)RFL((unsigned)(v7 >> 32)) << 32);

        float acc = 0.0f;

        // ---- prefix (j<320) from L2: r1's proven 8-in-flight loop ----
        for (int k = 0; k < cnt; k += 8) {
            int4 Ja = *(const int4*)(s_list + k);
            int4 Jb = *(const int4*)(s_list + k + 4);
            float g0 = wz[Ja.x * UNITS], g1 = wz[Ja.y * UNITS];
            float g2 = wz[Ja.z * UNITS], g3 = wz[Ja.w * UNITS];
            float g4 = wz[Jb.x * UNITS], g5 = wz[Jb.y * UNITS];
            float g6 = wz[Jb.z * UNITS], g7 = wz[Jb.w * UNITS];
            acc = __fadd_rn(acc, g0);
            acc = __fadd_rn(acc, g1);
            acc = __fadd_rn(acc, g2);
            acc = __fadd_rn(acc, g3);
            acc = __fadd_rn(acc, g4);
            acc = __fadd_rn(acc, g5);
            acc = __fadd_rn(acc, g6);
            acc = __fadd_rn(acc, g7);
        }

        // ---- tail (rows 320..511) from registers, uniform branches ----
#pragma unroll
        for (int k = 0; k < 64; ++k)
            if ((M5 >> k) & 1ull) acc = __fadd_rn(acc, tw[k]);
#pragma unroll
        for (int k = 0; k < 64; ++k)
            if ((M6 >> k) & 1ull) acc = __fadd_rn(acc, tw[64 + k]);
#pragma unroll
        for (int k = 0; k < 64; ++k)
            if ((M7 >> k) & 1ull) acc = __fadd_rn(acc, tw[128 + k]);

        // ---- elementwise state update — exact reference op order ----
        float newb = __fadd_rn(__fmul_rn(DECAY_B, ad), __fmul_rn(OMDB, z));
        float thr  = __fadd_rn(0.01f, __fmul_rn(newb, 1.6f));
        float it   = __fadd_rn(__fadd_rn(i_cur, acc), 0.0f);       // + ADD_CUR
        float ires = __fmul_rn(__fmul_rn(z, thr), 1.0f);           // * DT
        float newv = __fsub_rn(
            __fadd_rn(__fmul_rn(DECAY, v), __fmul_rn(OMD, it)), ires);
        float zn = (newv > thr) ? 1.0f : 0.0f;      // refractory is a no-op

        io[t * UNITS] = zn;
        v = newv; ad = newb; z = zn; i_cur = i_next;

        // ---- rebuild: prefix list (waves 0..4) + tail masks (waves 5..7) --
        unsigned long long m = __ballot(zn > 0.0f);
        if (w < 5 && lane == 0) s_cnt[w] = __popcll(m);
        __syncthreads();   // [A] all reads of old list/masks done

        int base = 0, total = 0;
#pragma unroll
        for (int i = 0; i < 5; ++i) {
            int c = s_cnt[i];
            total += c;
            if (i < w) base += c;
        }
        if (u < TST && zn > 0.0f) {
            int pos = base + __popcll(m & ((1ull << lane) - 1ull));
            s_list[pos] = u;
        }
        if (w >= 5 && lane == 0) s_tm[w - 5] = m;
        if (u == 0) s_total = total;
        if (u < 16) s_list[total + u] = UNITS;       // pad idx -> zero row
        __syncthreads();   // [C] list/masks ready
    }
#undef RFL
}

extern "C" void kernel_launch(void* const* d_in, const int* in_sizes, int n_in,
                              void* d_out, int out_size, void* d_ws, size_t ws_size,
                              hipStream_t stream) {
    (void)in_sizes; (void)n_in; (void)out_size; (void)ws_size;
    const float* x     = (const float*)d_in[0];   // [B,T,128]
    const float* W_in  = (const float*)d_in[1];   // [128,512]
    const float* W_rec = (const float*)d_in[2];   // [512,512]
    float* out = (float*)d_out;                   // [B,T,512]
    float* Wz  = (float*)d_ws;                    // [513][512] zero-diag copy

    wz_prep<<<dim3(UNITS + 1), dim3(UNITS), 0, stream>>>(W_rec, Wz);
    gemm_in<<<dim3((B_SZ * T_SZ / 128) * (UNITS / 128)), dim3(256), 0, stream>>>(
        x, W_in, out);
    alif_scan<<<dim3(B_SZ), dim3(512), 0, stream>>>(Wz, out);
}

// Round 14
// 3573.333 us; speedup vs baseline: 1.0211x; 1.0211x over previous
//
#include <hip/hip_runtime.h>
#include <stdint.h>

#define B_SZ   256
#define T_SZ   1000
#define N_IN   128
#define UNITS  512
#define NT     128                // tail rows in registers (384..511, waves 6-7)
#define TST    (UNITS - NT)       // 384

// ---------------------------------------------------------------------------
// Phase 0: Wz[513][512]: W_rec with diag zeroed + all-zero row 512. Pad-slot
// (idx 512) and diagonal reads give exact +0.0f (proven r5..r13, absmax 0.0).
// ---------------------------------------------------------------------------
__global__ __launch_bounds__(512) void wz_prep(const float* __restrict__ Wr,
                                               float* __restrict__ Wz) {
    const int c = threadIdx.x, r = blockIdx.x;
    Wz[(size_t)r * UNITS + c] =
        (r >= UNITS || r == c) ? 0.0f : Wr[(size_t)r * UNITS + c];
}

// ---------------------------------------------------------------------------
// Phase 1: C[M,512] = X[M,128] @ W[128,512]  (unchanged, ~fp32 roofline)
// ---------------------------------------------------------------------------
__global__ __launch_bounds__(256) void gemm_in(const float* __restrict__ X,
                                               const float* __restrict__ W,
                                               float* __restrict__ C) {
    __shared__ __align__(16) float As[32][128];
    __shared__ __align__(16) float Bs[32][128];

    const int tid = threadIdx.x;
    const int ntile = blockIdx.x & 3;
    const int mtile = blockIdx.x >> 2;
    const int m0 = mtile * 128, n0 = ntile * 128;
    const int tm  = (tid >> 4) * 8;
    const int tn4 = (tid & 15) * 4;

    float acc[8][8];
#pragma unroll
    for (int i = 0; i < 8; ++i)
#pragma unroll
        for (int j = 0; j < 8; ++j) acc[i][j] = 0.0f;

    for (int k0 = 0; k0 < 128; k0 += 32) {
        __syncthreads();
#pragma unroll
        for (int r = 0; r < 4; ++r) {
            int li  = r * 256 + tid;
            int row = li >> 3;
            int ch  = li & 7;
            float4 a = *(const float4*)&X[(size_t)(m0 + row) * 128 + k0 + ch * 4];
            As[ch * 4 + 0][row] = a.x;
            As[ch * 4 + 1][row] = a.y;
            As[ch * 4 + 2][row] = a.z;
            As[ch * 4 + 3][row] = a.w;
        }
#pragma unroll
        for (int r = 0; r < 4; ++r) {
            int li = r * 256 + tid;
            int kk = li >> 5;
            int n4 = li & 31;
            *(float4*)&Bs[kk][n4 * 4] =
                *(const float4*)&W[(size_t)(k0 + kk) * 512 + n0 + n4 * 4];
        }
        __syncthreads();

#pragma unroll 8
        for (int k = 0; k < 32; ++k) {
            float4 a0 = *(const float4*)&As[k][tm];
            float4 a1 = *(const float4*)&As[k][tm + 4];
            float4 b0 = *(const float4*)&Bs[k][tn4];
            float4 b1 = *(const float4*)&Bs[k][tn4 + 64];
            const float av[8] = {a0.x, a0.y, a0.z, a0.w, a1.x, a1.y, a1.z, a1.w};
            const float bv[8] = {b0.x, b0.y, b0.z, b0.w, b1.x, b1.y, b1.z, b1.w};
#pragma unroll
            for (int i = 0; i < 8; ++i)
#pragma unroll
                for (int j = 0; j < 8; ++j)
                    acc[i][j] = fmaf(av[i], bv[j], acc[i][j]);
        }
    }

#pragma unroll
    for (int i = 0; i < 8; ++i) {
        size_t row = (size_t)(m0 + tm + i) * 512;
        float4 c0 = make_float4(acc[i][0], acc[i][1], acc[i][2], acc[i][3]);
        float4 c1 = make_float4(acc[i][4], acc[i][5], acc[i][6], acc[i][7]);
        *(float4*)&C[row + n0 + tn4]      = c0;
        *(float4*)&C[row + n0 + 64 + tn4] = c1;
    }
}

// ---------------------------------------------------------------------------
// Phase 2: ALIF scan. One WG per batch (grid 256, 512 thr), thread u owns
// unit u. ~85% of the per-XCD L2-BW wall => cut 25% of W traffic at zero
// recurring memory cost: rows 384..511 (waves 6-7) of column u live in
// tw[128] REGISTERS (preloaded once; W constant across steps). Prefix
// (j<384) = r1's untouched 8-in-flight L2 loop over a 6-wave list. Tail =
// 128 BRANCH-FREE fmacs: acc = fmaf(tw[k], bb, acc), bb in {1,0} from the
// scalarized ballot masks (SALU bit tests; no branches — the r13 mistake).
// Exactness: fma(w,1,acc) rounds w+acc once == __fadd_rn(acc,w);
// fma(w,0,acc) == acc + (+/-0) == acc (acc is never -0.0). Global order =
// prefix actives ascending then rows 384..511 ascending with inactive rows
// exact no-ops — bit-identical to all passing rounds (absmax 0.0).
// ---------------------------------------------------------------------------
__global__ __launch_bounds__(512, 2) void alif_scan(const float* __restrict__ Wz,
                                                    float* __restrict__ IO) {
    __shared__ __align__(16) int s_list[TST + 16];   // <=384 actives + 16 pad
    __shared__ int s_cnt[6];
    __shared__ int s_total;
    __shared__ unsigned long long s_tm[2];           // ballot masks, waves 6,7

    const int b = blockIdx.x;
    const int u = threadIdx.x;
    const int w = u >> 6;
    const int lane = u & 63;

    const float DECAY   = 0.95122942450071400910f;   // exp(-1/20)
    const float OMD     = 1.0f - DECAY;
    const float DECAY_B = 0.99501247919268232342f;   // exp(-1/200)
    const float OMDB    = 1.0f - DECAY_B;

    float v = 0.0f, ad = 0.0f, z = 0.0f;

    const float* wz = Wz + u;                         // column u of Wz
    float* io = IO + (size_t)b * (T_SZ * UNITS) + u;

    // ---- one-time: preload tail rows 384..511 of column u into registers --
    float tw[NT];
#pragma unroll
    for (int k = 0; k < NT; ++k)
        tw[k] = Wz[(size_t)(TST + k) * UNITS + u];    // diag already zeroed

    // ---- init shared state ----
    if (u < TST + 16) s_list[u] = UNITS;
    if (u < 6) s_cnt[u] = 0;
    if (u < 2) s_tm[u] = 0ull;
    if (u == 0) s_total = 0;
    __syncthreads();

    float i_cur = io[0];

#define RFL(x) ((unsigned)__builtin_amdgcn_readfirstlane((int)(x)))

    for (int t = 0; t < T_SZ; ++t) {
        // prefetch next step's input current
        float i_next = io[(t + 1 < T_SZ ? t + 1 : t) * UNITS];

        const int cnt = s_total;          // prefix actives (j < 384)

        // scalarize tail masks (block-uniform -> SGPRs)
        unsigned long long v6 = s_tm[0], v7 = s_tm[1];
        const unsigned long long M6 =
            RFL((unsigned)v6) | ((unsigned long long)RFL((unsigned)(v6 >> 32)) << 32);
        const unsigned long long M7 =
            RFL((unsigned)v7) | ((unsigned long long)RFL((unsigned)(v7 >> 32)) << 32);

        float acc = 0.0f;

        // ---- prefix (j<384) from L2: r1's proven 8-in-flight loop ----
        for (int k = 0; k < cnt; k += 8) {
            int4 Ja = *(const int4*)(s_list + k);
            int4 Jb = *(const int4*)(s_list + k + 4);
            float g0 = wz[Ja.x * UNITS], g1 = wz[Ja.y * UNITS];
            float g2 = wz[Ja.z * UNITS], g3 = wz[Ja.w * UNITS];
            float g4 = wz[Jb.x * UNITS], g5 = wz[Jb.y * UNITS];
            float g6 = wz[Jb.z * UNITS], g7 = wz[Jb.w * UNITS];
            acc = __fadd_rn(acc, g0);
            acc = __fadd_rn(acc, g1);
            acc = __fadd_rn(acc, g2);
            acc = __fadd_rn(acc, g3);
            acc = __fadd_rn(acc, g4);
            acc = __fadd_rn(acc, g5);
            acc = __fadd_rn(acc, g6);
            acc = __fadd_rn(acc, g7);
        }

        // ---- tail (rows 384..511) from registers, branch-free fmacs ----
#pragma unroll
        for (int k = 0; k < 64; ++k) {
            float bb = ((M6 >> k) & 1ull) ? 1.0f : 0.0f;
            acc = fmaf(tw[k], bb, acc);
        }
#pragma unroll
        for (int k = 0; k < 64; ++k) {
            float bb = ((M7 >> k) & 1ull) ? 1.0f : 0.0f;
            acc = fmaf(tw[64 + k], bb, acc);
        }

        // ---- elementwise state update — exact reference op order ----
        float newb = __fadd_rn(__fmul_rn(DECAY_B, ad), __fmul_rn(OMDB, z));
        float thr  = __fadd_rn(0.01f, __fmul_rn(newb, 1.6f));
        float it   = __fadd_rn(__fadd_rn(i_cur, acc), 0.0f);       // + ADD_CUR
        float ires = __fmul_rn(__fmul_rn(z, thr), 1.0f);           // * DT
        float newv = __fsub_rn(
            __fadd_rn(__fmul_rn(DECAY, v), __fmul_rn(OMD, it)), ires);
        float zn = (newv > thr) ? 1.0f : 0.0f;      // refractory is a no-op

        io[t * UNITS] = zn;
        v = newv; ad = newb; z = zn; i_cur = i_next;

        // ---- rebuild: prefix list (waves 0..5) + tail masks (waves 6,7) --
        unsigned long long m = __ballot(zn > 0.0f);
        if (w < 6 && lane == 0) s_cnt[w] = __popcll(m);
        __syncthreads();   // [A] all reads of old list/masks done

        // tail masks written AFTER [A] (readers of old masks are pre-[A]),
        // visible at next step after [C]
        if (w >= 6 && lane == 0) s_tm[w - 6] = m;

        int base = 0, total = 0;
#pragma unroll
        for (int i = 0; i < 6; ++i) {
            int c = s_cnt[i];
            total += c;
            if (i < w) base += c;
        }
        if (w < 6 && zn > 0.0f) {
            int pos = base + __popcll(m & ((1ull << lane) - 1ull));
            s_list[pos] = u;
        }
        if (u == 0) s_total = total;
        if (u < 16) s_list[total + u] = UNITS;       // pad idx -> zero row
        __syncthreads();   // [C] list/masks ready
    }
#undef RFL
}

extern "C" void kernel_launch(void* const* d_in, const int* in_sizes, int n_in,
                              void* d_out, int out_size, void* d_ws, size_t ws_size,
                              hipStream_t stream) {
    (void)in_sizes; (void)n_in; (void)out_size; (void)ws_size;
    const float* x     = (const float*)d_in[0];   // [B,T,128]
    const float* W_in  = (const float*)d_in[1];   // [128,512]
    const float* W_rec = (const float*)d_in[2];   // [512,512]
    float* out = (float*)d_out;                   // [B,T,512]
    float* Wz  = (float*)d_ws;                    // [513][512] zero-diag copy

    wz_prep<<<dim3(UNITS + 1), dim3(UNITS), 0, stream>>>(W_rec, Wz);
    gemm_in<<<dim3((B_SZ * T_SZ / 128) * (UNITS / 128)), dim3(256), 0, stream>>>(
        x, W_in, out);
    alif_scan<<<dim3(B_SZ), dim3(512), 0, stream>>>(Wz, out);
}

// Round 15
// 2002.596 us; speedup vs baseline: 1.8220x; 1.7844x over previous
//
#include <hip/hip_runtime.h>

#define B_SZ   256
#define T_SZ   1000
#define N_IN   128
#define UNITS  512
#define NC     64        // rows of Wz cached in LDS; cache row NC = zero row

// dynamic LDS layout (4B words):
//   [0, 33280)      float lds_w[65][512]   (Wz rows 0..63 + zero row 64)
//   [33280, 33808)  int   list[528]        (512 + 16 pad slots of idx 512)
//   [33808, 33816)  int   s_cnt[8]
//   [33816, 33817)  int   s_total
#define SMEM_WORDS (33280 + 528 + 8 + 4)
#define SMEM_BYTES (SMEM_WORDS * 4)

// ---------------------------------------------------------------------------
// Phase 0: Wz[513][512]: W_rec with diag zeroed + all-zero row 512. Pad-slot
// (idx 512) and diagonal gathers return exact +0.0f -> unconditional add
// chain stays bit-identical to the predicated r1 chain (proven r5..r14).
// ---------------------------------------------------------------------------
__global__ __launch_bounds__(512) void wz_prep(const float* __restrict__ Wr,
                                               float* __restrict__ Wz) {
    const int c = threadIdx.x, r = blockIdx.x;
    Wz[(size_t)r * UNITS + c] =
        (r >= UNITS || r == c) ? 0.0f : Wr[(size_t)r * UNITS + c];
}

// ---------------------------------------------------------------------------
// Phase 1: C[M,512] = X[M,128] @ W[128,512]  (unchanged, ~fp32 roofline)
// ---------------------------------------------------------------------------
__global__ __launch_bounds__(256) void gemm_in(const float* __restrict__ X,
                                               const float* __restrict__ W,
                                               float* __restrict__ C) {
    __shared__ __align__(16) float As[32][128];
    __shared__ __align__(16) float Bs[32][128];

    const int tid = threadIdx.x;
    const int ntile = blockIdx.x & 3;
    const int mtile = blockIdx.x >> 2;
    const int m0 = mtile * 128, n0 = ntile * 128;
    const int tm  = (tid >> 4) * 8;
    const int tn4 = (tid & 15) * 4;

    float acc[8][8];
#pragma unroll
    for (int i = 0; i < 8; ++i)
#pragma unroll
        for (int j = 0; j < 8; ++j) acc[i][j] = 0.0f;

    for (int k0 = 0; k0 < 128; k0 += 32) {
        __syncthreads();
#pragma unroll
        for (int r = 0; r < 4; ++r) {
            int li  = r * 256 + tid;
            int row = li >> 3;
            int ch  = li & 7;
            float4 a = *(const float4*)&X[(size_t)(m0 + row) * 128 + k0 + ch * 4];
            As[ch * 4 + 0][row] = a.x;
            As[ch * 4 + 1][row] = a.y;
            As[ch * 4 + 2][row] = a.z;
            As[ch * 4 + 3][row] = a.w;
        }
#pragma unroll
        for (int r = 0; r < 4; ++r) {
            int li = r * 256 + tid;
            int kk = li >> 5;
            int n4 = li & 31;
            *(float4*)&Bs[kk][n4 * 4] =
                *(const float4*)&W[(size_t)(k0 + kk) * 512 + n0 + n4 * 4];
        }
        __syncthreads();

#pragma unroll 8
        for (int k = 0; k < 32; ++k) {
            float4 a0 = *(const float4*)&As[k][tm];
            float4 a1 = *(const float4*)&As[k][tm + 4];
            float4 b0 = *(const float4*)&Bs[k][tn4];
            float4 b1 = *(const float4*)&Bs[k][tn4 + 64];
            const float av[8] = {a0.x, a0.y, a0.z, a0.w, a1.x, a1.y, a1.z, a1.w};
            const float bv[8] = {b0.x, b0.y, b0.z, b0.w, b1.x, b1.y, b1.z, b1.w};
#pragma unroll
            for (int i = 0; i < 8; ++i)
#pragma unroll
                for (int j = 0; j < 8; ++j)
                    acc[i][j] = fmaf(av[i], bv[j], acc[i][j]);
        }
    }

#pragma unroll
    for (int i = 0; i < 8; ++i) {
        size_t row = (size_t)(m0 + tm + i) * 512;
        float4 c0 = make_float4(acc[i][0], acc[i][1], acc[i][2], acc[i][3]);
        float4 c1 = make_float4(acc[i][4], acc[i][5], acc[i][6], acc[i][7]);
        *(float4*)&C[row + n0 + tn4]      = c0;
        *(float4*)&C[row + n0 + 64 + tn4] = c1;
    }
}

// ---------------------------------------------------------------------------
// Phase 2: ALIF scan — the r9 configuration (best measured: scan ~1745 us,
// total 1995.8 us). One WG per batch (grid 256, 512 thr), thread u owns
// unit u. LDS-cached ascending PREFIX (rows 0..63) + r1's proven 8-in-flight
// global gather loop for the suffix. Single acc, globally ascending j;
// pads/diag read exact +0.0f — bit-identical to all passing rounds.
// ---------------------------------------------------------------------------
__global__ __launch_bounds__(512, 2) void alif_scan(const float* __restrict__ Wz,
                                                    float* __restrict__ IO) {
    extern __shared__ __align__(16) float smem[];
    float* lds_w   = smem;                            // [65][512]
    int*   lst     = (int*)(smem + (NC + 1) * UNITS); // [528]
    int*   s_cnt   = lst + 528;                       // [8]
    int*   s_total = s_cnt + 8;                       // [1]

    const int b = blockIdx.x;
    const int u = threadIdx.x;
    const int w = u >> 6;
    const int lane = u & 63;

    const float DECAY   = 0.95122942450071400910f;   // exp(-1/20)
    const float OMD     = 1.0f - DECAY;
    const float DECAY_B = 0.99501247919268232342f;   // exp(-1/200)
    const float OMDB    = 1.0f - DECAY_B;

    float v = 0.0f, ad = 0.0f, z = 0.0f;

    const float* wz = Wz + u;                         // column u of Wz
    float* io = IO + (size_t)b * (T_SZ * UNITS) + u;

    // ---- one-time init: stage LDS cache (Wz rows 0..63 + zero row 64) ----
    for (int idx = u; idx < (NC + 1) * UNITS; idx += 512) {
        lds_w[idx] = (idx < NC * UNITS) ? Wz[idx] : 0.0f;
    }
    lst[u] = UNITS;
    if (u < 16) lst[UNITS + u] = UNITS;
    if (u < 8) s_cnt[u] = 0;
    if (u == 0) *s_total = 0;
    __syncthreads();

    float i_cur = io[0];

    for (int t = 0; t < T_SZ; ++t) {
        // prefetch next step's input current
        float i_next = io[(t + 1 < T_SZ ? t + 1 : t) * UNITS];

        const int cnt = *s_total;
        const int c0  = s_cnt[0];          // actives with j < 64 (list prefix)
        float acc = 0.0f;

        // ---- prefix from LDS cache (zero L2 traffic) ----
        for (int k = 0; k < c0; k += 8) {
            int4 Ja = *(const int4*)(lst + k);
            int4 Jb = *(const int4*)(lst + k + 4);
            // tail overrun (suffix j>=64 or pads) clamps to zero row NC
            int j0 = min(Ja.x, NC), j1 = min(Ja.y, NC);
            int j2 = min(Ja.z, NC), j3 = min(Ja.w, NC);
            int j4 = min(Jb.x, NC), j5 = min(Jb.y, NC);
            int j6 = min(Jb.z, NC), j7 = min(Jb.w, NC);
            float g0 = lds_w[j0 * UNITS + u], g1 = lds_w[j1 * UNITS + u];
            float g2 = lds_w[j2 * UNITS + u], g3 = lds_w[j3 * UNITS + u];
            float g4 = lds_w[j4 * UNITS + u], g5 = lds_w[j5 * UNITS + u];
            float g6 = lds_w[j6 * UNITS + u], g7 = lds_w[j7 * UNITS + u];
            acc = __fadd_rn(acc, g0);
            acc = __fadd_rn(acc, g1);
            acc = __fadd_rn(acc, g2);
            acc = __fadd_rn(acc, g3);
            acc = __fadd_rn(acc, g4);
            acc = __fadd_rn(acc, g5);
            acc = __fadd_rn(acc, g6);
            acc = __fadd_rn(acc, g7);
        }

        // ---- suffix from L2: r1's proven 8-in-flight loop ----
        // starts 8-aligned below c0; pre-c0 slots read the Wz zero row
        for (int k = c0 & ~7; k < cnt; k += 8) {
            int4 Ja = *(const int4*)(lst + k);
            int4 Jb = *(const int4*)(lst + k + 4);
            int j0 = (k + 0 >= c0) ? Ja.x : UNITS;
            int j1 = (k + 1 >= c0) ? Ja.y : UNITS;
            int j2 = (k + 2 >= c0) ? Ja.z : UNITS;
            int j3 = (k + 3 >= c0) ? Ja.w : UNITS;
            int j4 = (k + 4 >= c0) ? Jb.x : UNITS;
            int j5 = (k + 5 >= c0) ? Jb.y : UNITS;
            int j6 = (k + 6 >= c0) ? Jb.z : UNITS;
            int j7 = (k + 7 >= c0) ? Jb.w : UNITS;
            float g0 = wz[j0 * UNITS], g1 = wz[j1 * UNITS];
            float g2 = wz[j2 * UNITS], g3 = wz[j3 * UNITS];
            float g4 = wz[j4 * UNITS], g5 = wz[j5 * UNITS];
            float g6 = wz[j6 * UNITS], g7 = wz[j7 * UNITS];
            acc = __fadd_rn(acc, g0);
            acc = __fadd_rn(acc, g1);
            acc = __fadd_rn(acc, g2);
            acc = __fadd_rn(acc, g3);
            acc = __fadd_rn(acc, g4);
            acc = __fadd_rn(acc, g5);
            acc = __fadd_rn(acc, g6);
            acc = __fadd_rn(acc, g7);
        }

        // ---- elementwise state update — exact reference op order ----
        float newb = __fadd_rn(__fmul_rn(DECAY_B, ad), __fmul_rn(OMDB, z));
        float thr  = __fadd_rn(0.01f, __fmul_rn(newb, 1.6f));
        float it   = __fadd_rn(__fadd_rn(i_cur, acc), 0.0f);       // + ADD_CUR
        float ires = __fmul_rn(__fmul_rn(z, thr), 1.0f);           // * DT
        float newv = __fsub_rn(
            __fadd_rn(__fmul_rn(DECAY, v), __fmul_rn(OMD, it)), ires);
        float zn = (newv > thr) ? 1.0f : 0.0f;      // refractory is a no-op

        io[t * UNITS] = zn;
        v = newv; ad = newb; z = zn; i_cur = i_next;

        // ---- rebuild contiguous ascending active list (r1 scheme) ----
        unsigned long long m = __ballot(zn > 0.0f);
        if (lane == 0) s_cnt[w] = __popcll(m);
        __syncthreads();   // [A] reads of old list done; counts visible

        int base = 0, total = 0;
#pragma unroll
        for (int i = 0; i < 8; ++i) {
            int c = s_cnt[i];
            total += c;
            if (i < w) base += c;
        }
        if (zn > 0.0f) {
            int pos = base + __popcll(m & ((1ull << lane) - 1ull));
            lst[pos] = u;
        }
        if (u == 0) *s_total = total;
        if (u < 16) lst[total + u] = UNITS;          // pad idx -> zero row
        __syncthreads();   // [C] list ready
    }
}

extern "C" void kernel_launch(void* const* d_in, const int* in_sizes, int n_in,
                              void* d_out, int out_size, void* d_ws, size_t ws_size,
                              hipStream_t stream) {
    (void)in_sizes; (void)n_in; (void)out_size; (void)ws_size;
    const float* x     = (const float*)d_in[0];   // [B,T,128]
    const float* W_in  = (const float*)d_in[1];   // [128,512]
    const float* W_rec = (const float*)d_in[2];   // [512,512]
    float* out = (float*)d_out;                   // [B,T,512]
    float* Wz  = (float*)d_ws;                    // [513][512] zero-diag copy

    wz_prep<<<dim3(UNITS + 1), dim3(UNITS), 0, stream>>>(W_rec, Wz);
    gemm_in<<<dim3((B_SZ * T_SZ / 128) * (UNITS / 128)), dim3(256), 0, stream>>>(
        x, W_in, out);

    hipFuncSetAttribute((const void*)alif_scan,
                        hipFuncAttributeMaxDynamicSharedMemorySize, SMEM_BYTES);
    alif_scan<<<dim3(B_SZ), dim3(512), SMEM_BYTES, stream>>>(Wz, out);
}